// Round 6
// baseline (408.984 us; speedup 1.0000x reference)
//
#include <hip/hip_runtime.h>

#define B_ 64
#define I_ 1152
#define C_ 32
#define E_ 16
#define D_ 8
#define BC_ 16                // batch rows per block (4 waves, j=4 each)
#define ICt 6                 // i's per block
#define NIC (I_/ICt)          // 192 i-chunks
#define SCE (B_*C_*E_)        // 32768 s-elements
#define NBLK (NIC*(B_/BC_))   // 768 blocks = 3 per CU (guaranteed resident)
#define WROW4 (C_*D_*E_/4)    // 1024 float4 per W[i]

// async global->LDS DMA, 16B per lane (dest = wave-uniform base + lane*16)
__device__ __forceinline__ void gload_lds16(const void* g, void* l) {
  typedef __attribute__((address_space(1))) const void GV;
  typedef __attribute__((address_space(3))) void LV;
  __builtin_amdgcn_global_load_lds((GV*)g, (LV*)l, 16, 0, 0);
}

// Two-level grid barrier. bar layout (unsigned): leaves at [k*16] k=0..7,
// root at [128], generation at [144]. All counters zeroed by host memset.
// Device-scope atomics + __threadfence give cross-XCD visibility (G16).
__device__ __forceinline__ void grid_barrier(unsigned* bar) {
  __syncthreads();                       // all block's memory ops drained
  if (threadIdx.x == 0) {
    unsigned* leaf = bar + ((blockIdx.x & 7) << 4);
    unsigned* root = bar + 128;
    unsigned* genp = bar + 144;
    unsigned g = __atomic_load_n(genp, __ATOMIC_RELAXED);   // snapshot BEFORE arrive
    __threadfence();                     // release: publish partial/vacc stores
    if (atomicAdd(leaf, 1u) == (NBLK/8 - 1u)) {
      atomicExch(leaf, 0u);              // reset for next barrier
      __threadfence();
      if (atomicAdd(root, 1u) == 7u) {
        atomicExch(root, 0u);
        __threadfence();
        atomicAdd(genp, 1u);             // open the gate
      }
    }
    while (__atomic_load_n(genp, __ATOMIC_RELAXED) == g)
      __builtin_amdgcn_s_sleep(2);
    __threadfence();                     // acquire: see other blocks' stores
  }
  __syncthreads();
}

// One persistent kernel: 3 x (recompute-u_hat pass -> partial, grid barrier,
// reduce+squash, grid barrier). Block: ic = bid>>2 (6 i's), bslab = bid&3
// (16 b's). Thread: c=t&31, eh=(t>>5)&1, bq=t>>6, j=0..3 -> b=b0+bq*4+j.
// W double-buffered via global_load_lds; swizzle (quad rotated by c-row)
// applied on the GLOBAL source address, LDS dest linear (rule 21).
__global__ __launch_bounds__(256, 3)
void caps_fused(const float* __restrict__ x, const float* __restrict__ W,
                float* __restrict__ partial, float* __restrict__ vacc,
                float* __restrict__ out, unsigned* __restrict__ bar)
{
  __shared__ float4 Wl[2][C_*32];     // 2 x 16KB W buffers
  __shared__ float4 xl[BC_*ICt*2];    // 192 float4 (3KB), persists all passes

  const int t  = threadIdx.x;
  const int c  = t & 31;
  const int eh = (t >> 5) & 1;
  const int bq = t >> 6;
  const int ic = blockIdx.x >> 2;     // 0..191
  const int i0 = ic * ICt;
  const int b0 = (blockIdx.x & 3) * BC_;

  // DMA staging map: LDS linear float4 index gidx = t + 256k; row cc = gidx>>5,
  // slot = gidx&31 = c. Want Wl[cc*32 + ((q+cc)&31)] = wg[cc*32+q]
  // => src quad f = cc*32 + ((c - cc)&31).
  int fsrc[4];
#pragma unroll
  for (int k = 0; k < 4; ++k) {
    int cc = (t >> 5) + 8*k;
    fsrc[k] = cc*32 + ((c - cc) & 31);
  }
  const float4* wg = (const float4*)(W + (size_t)i0 * (C_*D_*E_));

  // stage x once for all 3 passes (16 b x 6 i x 8 d)
  if (t < BC_*ICt*2) {
    int b = t / (ICt*2), r = t % (ICt*2);
    xl[t] = ((const float4*)x)[ ((size_t)(b0 + b)*I_ + i0)*2 + r ];
  }

  for (int iter = 0; iter < 3; ++iter) {
    const bool route = (iter > 0);

    float vr[4][8];
    if (route) {
#pragma unroll
      for (int j = 0; j < 4; ++j) {
        const float4* vp = (const float4*)(vacc + (((size_t)(b0 + bq*4 + j)*C_ + c)*E_ + eh*8));
        float4 a = vp[0], b = vp[1];
        vr[j][0]=a.x; vr[j][1]=a.y; vr[j][2]=a.z; vr[j][3]=a.w;
        vr[j][4]=b.x; vr[j][5]=b.y; vr[j][6]=b.z; vr[j][7]=b.w;
      }
    }

    float acc[4][8];
#pragma unroll
    for (int j = 0; j < 4; ++j)
#pragma unroll
      for (int e = 0; e < 8; ++e) acc[j][e] = 0.f;

    // prologue: W[i0] -> buf0 (async DMA)
#pragma unroll
    for (int k = 0; k < 4; ++k)
      gload_lds16(wg + fsrc[k], &Wl[0][t + 256*k]);
    __syncthreads();                    // drains DMA (and xl at iter 0)

    int cur = 0;
    for (int ii = 0; ii < ICt; ++ii) {
      if (ii + 1 < ICt) {               // prefetch next W; flies under compute
        const float4* wn = wg + (size_t)(ii + 1) * WROW4;
#pragma unroll
        for (int k = 0; k < 4; ++k)
          gload_lds16(wn + fsrc[k], &Wl[cur^1][t + 256*k]);
      }

      float xv[4][8];
#pragma unroll
      for (int j = 0; j < 4; ++j) {
        float4 a = xl[(bq*4 + j)*(ICt*2) + ii*2 + 0];
        float4 b = xl[(bq*4 + j)*(ICt*2) + ii*2 + 1];
        xv[j][0]=a.x; xv[j][1]=a.y; xv[j][2]=a.z; xv[j][3]=a.w;
        xv[j][4]=b.x; xv[j][5]=b.y; xv[j][6]=b.z; xv[j][7]=b.w;
      }

      float uh[4][8];
#pragma unroll
      for (int j = 0; j < 4; ++j)
#pragma unroll
        for (int e = 0; e < 8; ++e) uh[j][e] = 0.f;

#pragma unroll
      for (int d = 0; d < D_; ++d) {
#pragma unroll
        for (int qq = 0; qq < 2; ++qq) {
          float4 wv = Wl[cur][c*32 + (((d*4 + eh*2 + qq) + c) & 31)];
          const int eb = qq*4;
#pragma unroll
          for (int j = 0; j < 4; ++j) {
            uh[j][eb+0] = fmaf(xv[j][d], wv.x, uh[j][eb+0]);
            uh[j][eb+1] = fmaf(xv[j][d], wv.y, uh[j][eb+1]);
            uh[j][eb+2] = fmaf(xv[j][d], wv.z, uh[j][eb+2]);
            uh[j][eb+3] = fmaf(xv[j][d], wv.w, uh[j][eb+3]);
          }
        }
      }

      float coef[4];
      if (route) {
#pragma unroll
        for (int j = 0; j < 4; ++j) {
          float lg = 0.f;
#pragma unroll
          for (int e = 0; e < 8; ++e) lg = fmaf(uh[j][e], vr[j][e], lg);
          lg += __shfl_xor(lg, 32, 64);           // combine e-halves
          float m = lg;
#pragma unroll
          for (int mk = 16; mk >= 1; mk >>= 1) m = fmaxf(m, __shfl_xor(m, mk, 64));
          float p = __expf(lg - m);
          float s = p;
#pragma unroll
          for (int mk = 16; mk >= 1; mk >>= 1) s += __shfl_xor(s, mk, 64);
          coef[j] = p * __builtin_amdgcn_rcpf(s);
        }
      } else {
#pragma unroll
        for (int j = 0; j < 4; ++j) coef[j] = (1.0f / C_);
      }

#pragma unroll
      for (int j = 0; j < 4; ++j)
#pragma unroll
        for (int e = 0; e < 8; ++e) acc[j][e] = fmaf(coef[j], uh[j][e], acc[j][e]);

      __syncthreads();                  // next buf DMA complete; guards reuse
      cur ^= 1;
    }

    // write partial s for this i-chunk: [NIC][B][C][E]
#pragma unroll
    for (int j = 0; j < 4; ++j) {
      size_t base = ((size_t)ic * B_ + (b0 + bq*4 + j)) * (C_*E_) + (size_t)c*E_ + eh*8;
      float4 o0 = {acc[j][0],acc[j][1],acc[j][2],acc[j][3]};
      float4 o1 = {acc[j][4],acc[j][5],acc[j][6],acc[j][7]};
      *(float4*)(partial + base)     = o0;
      *(float4*)(partial + base + 4) = o1;
    }

    grid_barrier(bar);                  // partial complete, device-visible

    // reduce + squash: blocks 0..127 cover all 32768 cells
    const int gidx = blockIdx.x * 256 + t;
    if (gidx < SCE) {
      float s = 0.f;
#pragma unroll 12
      for (int k = 0; k < NIC; ++k) s += partial[(size_t)k * SCE + gidx];
      float sq = s * s;
      sq += __shfl_xor(sq, 1); sq += __shfl_xor(sq, 2);
      sq += __shfl_xor(sq, 4); sq += __shfl_xor(sq, 8);
      float scale = sq / (1.f + sq) / (sqrtf(sq) + 1e-8f);
      float v = scale * s;
      if (iter == 0)      vacc[gidx] = v;
      else if (iter == 1) vacc[gidx] += v;
      else                out[gidx]  = v;
    }

    if (iter < 2) grid_barrier(bar);    // vacc ready for next pass
  }
}

extern "C" void kernel_launch(void* const* d_in, const int* in_sizes, int n_in,
                              void* d_out, int out_size, void* d_ws, size_t ws_size,
                              hipStream_t stream)
{
  const float* x = (const float*)d_in[0];
  const float* W = (const float*)d_in[1];
  float* out     = (float*)d_out;

  float* partial = (float*)d_ws;                     // NIC*SCE f32 = 25.2 MB
  float* vacc    = partial + (size_t)NIC * SCE;      // SCE f32 = 128 KB
  unsigned* bar  = (unsigned*)(vacc + SCE);          // 256 unsigned

  // barrier state must start at zero (ws is poisoned 0xAA by harness)
  hipMemsetAsync(bar, 0, 256 * sizeof(unsigned), stream);

  caps_fused<<<NBLK, 256, 0, stream>>>(x, W, partial, vacc, out, bar);
}

// Round 7
// 101.409 us; speedup vs baseline: 4.0330x; 4.0330x over previous
//
#include <hip/hip_runtime.h>

#define B_ 64
#define I_ 1152
#define C_ 32
#define E_ 16
#define D_ 8
#define BC_ 8                // batch rows per block (4 waves, j=2 each)
#define ICt 8                // i's per block
#define NIC (I_/ICt)         // 144 i-chunks
#define ICX (NIC/8)          // 18 i-chunks per XCD slab
#define WROW4 (C_*D_*E_/4)   // 1024 float4 per W[i]
#define SCE (B_*C_*E_)       // 32768 s-elements

// async global->LDS DMA, 16B per lane (dest = wave-uniform base + lane*16)
__device__ __forceinline__ void gload_lds16(const void* g, void* l) {
  typedef __attribute__((address_space(1))) const void GV;
  typedef __attribute__((address_space(3))) void LV;
  __builtin_amdgcn_global_load_lds((GV*)g, (LV*)l, 16, 0, 0);
}

// Recompute u_hat[b,i,c,e] = sum_d x[b,i,d]*W[i,c,d,e]; coupling coef (uniform
// or softmax_c of u_hat . vacc); accumulate partial s over the block's i-chunk.
// 256 thr: c=t&31, eh=(t>>5)&1, bq=t>>6 (0..3), j=0..1 -> b = b0 + bq*2 + j.
// W double-buffered via global_load_lds; swizzle (quad rotated by c-row)
// applied on the GLOBAL source address, LDS dest linear (rule 21).
// Block map (XCD slab swizzle, perf-only): xcd = bid&7 -> ic slab of ICX
// chunks; all 8 b-slabs of an ic dispatch consecutively on one XCD, so the
// slab's W (2.36 MB) stays L2-resident and is read from HBM once per pass.
template<bool ROUTE>
__global__ __launch_bounds__(256)
void caps_pass(const float* __restrict__ x, const float* __restrict__ W,
               const float* __restrict__ vacc, float* __restrict__ partial)
{
  __shared__ float4 Wl[2][C_*32];     // 2 x 16KB W buffers
  __shared__ float4 xl[BC_*ICt*2];    // 128 float4 (2KB)

  const int t   = threadIdx.x;
  const int c   = t & 31;
  const int eh  = (t >> 5) & 1;
  const int bq  = t >> 6;
  const int xcd = blockIdx.x & 7;
  const int sl  = blockIdx.x >> 3;    // 0..143
  const int ic  = xcd * ICX + (sl >> 3);
  const int b0  = (sl & 7) * BC_;
  const int i0  = ic * ICt;

  // DMA staging map: LDS linear float4 index g = t + 256k; row cc = g>>5,
  // slot = g&31 = c. Want Wl[cc*32 + ((q+cc)&31)] = wg[cc*32+q]
  // => src quad f = cc*32 + ((c - cc)&31).
  int fsrc[4];
#pragma unroll
  for (int k = 0; k < 4; ++k) {
    int cc = (t >> 5) + 8*k;
    fsrc[k] = cc*32 + ((c - cc) & 31);
  }

  const float4* wg = (const float4*)(W + (size_t)i0 * (C_*D_*E_));
  // prologue: issue W[i0] -> buf0 (async DMA)
#pragma unroll
  for (int k = 0; k < 4; ++k)
    gload_lds16(wg + fsrc[k], &Wl[0][t + 256*k]);

  // stage x for all ICt i's (128 float4: 8 b x 16)
  if (t < BC_*ICt*2) {
    int b = t >> 4, r = t & 15;                  // ICt*2 == 16
    xl[t] = ((const float4*)x)[ ((size_t)(b0 + b)*I_ + i0)*2 + r ];
  }

  float vr[2][8];
  if (ROUTE) {
#pragma unroll
    for (int j = 0; j < 2; ++j) {
      const float4* vp = (const float4*)(vacc + (((size_t)(b0 + bq*2 + j)*C_ + c)*E_ + eh*8));
      float4 a = vp[0], b = vp[1];
      vr[j][0]=a.x; vr[j][1]=a.y; vr[j][2]=a.z; vr[j][3]=a.w;
      vr[j][4]=b.x; vr[j][5]=b.y; vr[j][6]=b.z; vr[j][7]=b.w;
    }
  }

  float acc[2][8];
#pragma unroll
  for (int j = 0; j < 2; ++j)
#pragma unroll
    for (int e = 0; e < 8; ++e) acc[j][e] = 0.f;

  __syncthreads();   // drains vmcnt(0): buf0 + xl ready

  int cur = 0;
  for (int ii = 0; ii < ICt; ++ii) {
    if (ii + 1 < ICt) {                          // prefetch next W into other buffer
      const float4* wn = wg + (size_t)(ii + 1) * WROW4;
#pragma unroll
      for (int k = 0; k < 4; ++k)
        gload_lds16(wn + fsrc[k], &Wl[cur^1][t + 256*k]);
    }

    float xv[2][8];
#pragma unroll
    for (int j = 0; j < 2; ++j) {
      float4 a = xl[(bq*2 + j)*16 + ii*2 + 0];
      float4 b = xl[(bq*2 + j)*16 + ii*2 + 1];
      xv[j][0]=a.x; xv[j][1]=a.y; xv[j][2]=a.z; xv[j][3]=a.w;
      xv[j][4]=b.x; xv[j][5]=b.y; xv[j][6]=b.z; xv[j][7]=b.w;
    }

    float uh[2][8];
#pragma unroll
    for (int j = 0; j < 2; ++j)
#pragma unroll
      for (int e = 0; e < 8; ++e) uh[j][e] = 0.f;

#pragma unroll
    for (int d = 0; d < D_; ++d) {
#pragma unroll
      for (int qq = 0; qq < 2; ++qq) {
        float4 wv = Wl[cur][c*32 + (((d*4 + eh*2 + qq) + c) & 31)];
        const int eb = qq*4;
#pragma unroll
        for (int j = 0; j < 2; ++j) {
          uh[j][eb+0] = fmaf(xv[j][d], wv.x, uh[j][eb+0]);
          uh[j][eb+1] = fmaf(xv[j][d], wv.y, uh[j][eb+1]);
          uh[j][eb+2] = fmaf(xv[j][d], wv.z, uh[j][eb+2]);
          uh[j][eb+3] = fmaf(xv[j][d], wv.w, uh[j][eb+3]);
        }
      }
    }

    float coef[2];
    if (ROUTE) {
#pragma unroll
      for (int j = 0; j < 2; ++j) {
        float lg = 0.f;
#pragma unroll
        for (int e = 0; e < 8; ++e) lg = fmaf(uh[j][e], vr[j][e], lg);
        lg += __shfl_xor(lg, 32, 64);            // combine e-halves
        float m = lg;
#pragma unroll
        for (int mk = 16; mk >= 1; mk >>= 1) m = fmaxf(m, __shfl_xor(m, mk, 64));
        float p = __expf(lg - m);
        float s = p;
#pragma unroll
        for (int mk = 16; mk >= 1; mk >>= 1) s += __shfl_xor(s, mk, 64);
        coef[j] = p * __builtin_amdgcn_rcpf(s);
      }
    } else {
#pragma unroll
      for (int j = 0; j < 2; ++j) coef[j] = (1.0f / C_);
    }

#pragma unroll
    for (int j = 0; j < 2; ++j)
#pragma unroll
      for (int e = 0; e < 8; ++e) acc[j][e] = fmaf(coef[j], uh[j][e], acc[j][e]);

    __syncthreads();   // next buf DMA complete; guards buf reuse
    cur ^= 1;
  }

  // partial s for this i-chunk: [NIC][B][C][E]
#pragma unroll
  for (int j = 0; j < 2; ++j) {
    size_t base = ((size_t)ic * B_ + (b0 + bq*2 + j)) * (C_*E_) + (size_t)c*E_ + eh*8;
    float4 o0 = {acc[j][0],acc[j][1],acc[j][2],acc[j][3]};
    float4 o1 = {acc[j][4],acc[j][5],acc[j][6],acc[j][7]};
    *(float4*)(partial + base)     = o0;
    *(float4*)(partial + base + 4) = o1;
  }
}

// stage 1: red[ko][idx] = sum of ICX i-chunks
__global__ __launch_bounds__(256)
void reduce1(const float* __restrict__ partial, float* __restrict__ red)
{
  const int idx = blockIdx.x*256 + threadIdx.x;
  const int ko  = blockIdx.y;                     // 0..7
  const float* p = partial + (size_t)(ko*ICX) * SCE + idx;
  float s = 0.f;
#pragma unroll 9
  for (int k = 0; k < ICX; ++k) s += p[(size_t)k * SCE];
  red[(size_t)ko * SCE + idx] = s;
}

// stage 2: sum 8 split-k slabs, squash over e (16-lane groups).
// mode 0: vacc_out = v ; 1: vacc_out = vacc_in + v ; 2: vout = v
__global__ __launch_bounds__(256)
void reduce2(const float* __restrict__ red, const float* __restrict__ vacc_in,
             float* __restrict__ vacc_out, float* __restrict__ vout, int mode)
{
  const int idx = blockIdx.x*256 + threadIdx.x;
  float s = 0.f;
#pragma unroll
  for (int k = 0; k < 8; ++k) s += red[(size_t)k * SCE + idx];
  float sq = s * s;
  sq += __shfl_xor(sq, 1); sq += __shfl_xor(sq, 2);
  sq += __shfl_xor(sq, 4); sq += __shfl_xor(sq, 8);
  float scale = sq / (1.f + sq) / (sqrtf(sq) + 1e-8f);
  float v = scale * s;
  if (mode == 0)      vacc_out[idx] = v;
  else if (mode == 1) vacc_out[idx] = vacc_in[idx] + v;
  else                vout[idx] = v;
}

extern "C" void kernel_launch(void* const* d_in, const int* in_sizes, int n_in,
                              void* d_out, int out_size, void* d_ws, size_t ws_size,
                              hipStream_t stream)
{
  const float* x = (const float*)d_in[0];
  const float* W = (const float*)d_in[1];
  float* out     = (float*)d_out;

  float* partial = (float*)d_ws;                   // NIC*SCE f32 = 18.9 MB
  float* red     = partial + (size_t)NIC * SCE;    // 8*SCE f32 = 1 MB
  float* vacc    = red + 8 * SCE;                  // SCE f32 = 128 KB

  dim3 pg(NIC * (B_/BC_));                         // 1152 blocks
  dim3 rg1(SCE/256, 8);                            // 128 x 8
  const int rg2 = SCE/256;                         // 128

  // iter 0: uniform coefficients (softmax of zeros = 1/32)
  caps_pass<false><<<pg, 256, 0, stream>>>(x, W, nullptr, partial);
  reduce1<<<rg1, 256, 0, stream>>>(partial, red);
  reduce2<<<rg2, 256, 0, stream>>>(red, nullptr, vacc, nullptr, 0);
  // iter 1: logits = u_hat . v0
  caps_pass<true ><<<pg, 256, 0, stream>>>(x, W, vacc, partial);
  reduce1<<<rg1, 256, 0, stream>>>(partial, red);
  reduce2<<<rg2, 256, 0, stream>>>(red, vacc, vacc, nullptr, 1);
  // iter 2: logits = u_hat . (v0+v1)
  caps_pass<true ><<<pg, 256, 0, stream>>>(x, W, vacc, partial);
  reduce1<<<rg1, 256, 0, stream>>>(partial, red);
  reduce2<<<rg2, 256, 0, stream>>>(red, nullptr, nullptr, out, 2);
}

// Round 8
// 88.922 us; speedup vs baseline: 4.5993x; 1.1404x over previous
//
#include <hip/hip_runtime.h>

#define B_ 64
#define I_ 1152
#define C_ 32
#define E_ 16
#define D_ 8
#define BC_ 8                // batch rows per block (4 waves, j=2 each)
#define ICt 8                // i's per block
#define NIC (I_/ICt)         // 144 i-chunks
#define ICX (NIC/8)          // 18 i-chunks per XCD slab
#define WROW4 (C_*D_*E_/4)   // 1024 float4 per W[i]
#define SCE (B_*C_*E_)       // 32768 s-elements

// async global->LDS DMA, 16B per lane (dest = wave-uniform base + lane*16)
__device__ __forceinline__ void gload_lds16(const void* g, void* l) {
  typedef __attribute__((address_space(1))) const void GV;
  typedef __attribute__((address_space(3))) void LV;
  __builtin_amdgcn_global_load_lds((GV*)g, (LV*)l, 16, 0, 0);
}

#define WAITVM(N) do { asm volatile("s_waitcnt vmcnt(" #N ")" ::: "memory"); \
                       __builtin_amdgcn_sched_barrier(0); } while (0)
#define WAITLG0()  do { asm volatile("s_waitcnt lgkmcnt(0)" ::: "memory");   \
                       __builtin_amdgcn_sched_barrier(0); } while (0)

// Recompute u_hat[b,i,c,e] = sum_d x[b,i,d]*W[i,c,d,e]; coupling coef (uniform
// or softmax_c of u_hat . vacc, WITHOUT max-subtraction: logits bounded, f32
// exp safe); accumulate partial s over the block's i-chunk.
// 256 thr: c=t&31, eh=(t>>5)&1, bq=t>>6, j=0..1 -> b = b0 + bq*2 + j.
// W staged via global_load_lds into a 3-buffer, 2-deep pipeline with counted
// vmcnt + raw barriers (T3/T4): the per-period wait targets W(p) issued TWO
// periods earlier, so W(p+1),W(p+2) stay in flight across barriers.
// Period p: {lgkm(0); bar} issue DMA(p+2) {vmcnt(8); bar} compute(p).
// Swizzle (quad rotated by c-row) on the GLOBAL source address (rule 21).
// Block map (XCD slab, perf-only): xcd=bid&7 -> ic slab; slab W (2.36MB)
// stays L2-resident across the 8 b-slabs.
template<bool ROUTE>
__global__ __launch_bounds__(256)
void caps_pass(const float* __restrict__ x, const float* __restrict__ W,
               const float* __restrict__ vacc, float* __restrict__ partial)
{
  __shared__ float4 Wl[3][C_*32];     // 3 x 16KB W buffers
  __shared__ float4 xl[BC_*ICt*2];    // 128 float4 (2KB)

  const int t   = threadIdx.x;
  const int c   = t & 31;
  const int eh  = (t >> 5) & 1;
  const int bq  = t >> 6;
  const int xcd = blockIdx.x & 7;
  const int sl  = blockIdx.x >> 3;    // 0..143
  const int ic  = xcd * ICX + (sl >> 3);
  const int b0  = (sl & 7) * BC_;
  const int i0  = ic * ICt;

  // DMA staging map: LDS linear float4 index g = t + 256k; row cc = g>>5,
  // slot = g&31 = c. Want Wl[cc*32 + ((q+cc)&31)] = wg[cc*32+q]
  // => src quad f = cc*32 + ((c - cc)&31).
  int fsrc[4];
#pragma unroll
  for (int k = 0; k < 4; ++k) {
    int cc = (t >> 5) + 8*k;
    fsrc[k] = cc*32 + ((c - cc) & 31);
  }

  float vr[2][8];
  if (ROUTE) {
#pragma unroll
    for (int j = 0; j < 2; ++j) {
      const float4* vp = (const float4*)(vacc + (((size_t)(b0 + bq*2 + j)*C_ + c)*E_ + eh*8));
      float4 a = vp[0], b = vp[1];
      vr[j][0]=a.x; vr[j][1]=a.y; vr[j][2]=a.z; vr[j][3]=a.w;
      vr[j][4]=b.x; vr[j][5]=b.y; vr[j][6]=b.z; vr[j][7]=b.w;
    }
  }

  // stage x for all ICt i's (128 float4: 8 b x 16)
  if (t < BC_*ICt*2) {
    int b = t >> 4, r = t & 15;                  // ICt*2 == 16
    xl[t] = ((const float4*)x)[ ((size_t)(b0 + b)*I_ + i0)*2 + r ];
  }

  const float4* wg = (const float4*)(W + (size_t)i0 * (C_*D_*E_));
  // prologue: issue W[i0]->buf0 and W[i0+1]->buf1 (stay in flight)
#pragma unroll
  for (int k = 0; k < 4; ++k) gload_lds16(wg + fsrc[k],          &Wl[0][t + 256*k]);
#pragma unroll
  for (int k = 0; k < 4; ++k) gload_lds16(wg + WROW4 + fsrc[k],  &Wl[1][t + 256*k]);

  float acc[2][8];
#pragma unroll
  for (int j = 0; j < 2; ++j)
#pragma unroll
    for (int e = 0; e < 8; ++e) acc[j][e] = 0.f;

  int cur = 0;
  for (int ii = 0; ii < ICt; ++ii) {
    // barrier 1: all waves done READING the buffer DMA(ii+2) will overwrite
    // (and, at ii=0, xl ds_writes drained)
    WAITLG0();
    __builtin_amdgcn_s_barrier();
    __builtin_amdgcn_sched_barrier(0);

    if (ii + 2 < ICt) {                          // issue 2-ahead prefetch
      int pre = cur + 2; if (pre >= 3) pre -= 3;
      const float4* wn = wg + (size_t)(ii + 2) * WROW4;
#pragma unroll
      for (int k = 0; k < 4; ++k)
        gload_lds16(wn + fsrc[k], &Wl[pre][t + 256*k]);
    }

    // wait for OWN W(ii) batch (leaves W(ii+1),W(ii+2) in flight), then
    // barrier 2: every wave's W(ii) quarter has landed.
    if (ii < ICt - 2)       WAITVM(8);
    else if (ii == ICt - 2) WAITVM(4);
    else                    WAITVM(0);
    __builtin_amdgcn_s_barrier();
    __builtin_amdgcn_sched_barrier(0);

    float xv[2][8];
#pragma unroll
    for (int j = 0; j < 2; ++j) {
      float4 a = xl[(bq*2 + j)*16 + ii*2 + 0];
      float4 b = xl[(bq*2 + j)*16 + ii*2 + 1];
      xv[j][0]=a.x; xv[j][1]=a.y; xv[j][2]=a.z; xv[j][3]=a.w;
      xv[j][4]=b.x; xv[j][5]=b.y; xv[j][6]=b.z; xv[j][7]=b.w;
    }

    float uh[2][8];
#pragma unroll
    for (int j = 0; j < 2; ++j)
#pragma unroll
      for (int e = 0; e < 8; ++e) uh[j][e] = 0.f;

#pragma unroll
    for (int d = 0; d < D_; ++d) {
#pragma unroll
      for (int qq = 0; qq < 2; ++qq) {
        float4 wv = Wl[cur][c*32 + (((d*4 + eh*2 + qq) + c) & 31)];
        const int eb = qq*4;
#pragma unroll
        for (int j = 0; j < 2; ++j) {
          uh[j][eb+0] = fmaf(xv[j][d], wv.x, uh[j][eb+0]);
          uh[j][eb+1] = fmaf(xv[j][d], wv.y, uh[j][eb+1]);
          uh[j][eb+2] = fmaf(xv[j][d], wv.z, uh[j][eb+2]);
          uh[j][eb+3] = fmaf(xv[j][d], wv.w, uh[j][eb+3]);
        }
      }
    }

    float coef[2];
    if (ROUTE) {
#pragma unroll
      for (int j = 0; j < 2; ++j) {
        float lg = 0.f;
#pragma unroll
        for (int e = 0; e < 8; ++e) lg = fmaf(uh[j][e], vr[j][e], lg);
        lg += __shfl_xor(lg, 32, 64);            // combine e-halves
        // no max-subtraction: |lg| small, f32 exp exact enough & overflow-safe
        float p = __expf(lg);
        float s = p;
#pragma unroll
        for (int mk = 16; mk >= 1; mk >>= 1) s += __shfl_xor(s, mk, 64);
        coef[j] = p * __builtin_amdgcn_rcpf(s);
      }
    } else {
#pragma unroll
      for (int j = 0; j < 2; ++j) coef[j] = (1.0f / C_);
    }

#pragma unroll
    for (int j = 0; j < 2; ++j)
#pragma unroll
      for (int e = 0; e < 8; ++e) acc[j][e] = fmaf(coef[j], uh[j][e], acc[j][e]);

    cur = (cur + 1 == 3) ? 0 : cur + 1;
  }

  // partial s for this i-chunk: [NIC][B][C][E]
#pragma unroll
  for (int j = 0; j < 2; ++j) {
    size_t base = ((size_t)ic * B_ + (b0 + bq*2 + j)) * (C_*E_) + (size_t)c*E_ + eh*8;
    float4 o0 = {acc[j][0],acc[j][1],acc[j][2],acc[j][3]};
    float4 o1 = {acc[j][4],acc[j][5],acc[j][6],acc[j][7]};
    *(float4*)(partial + base)     = o0;
    *(float4*)(partial + base + 4) = o1;
  }
}

// Fused reduce+squash: grid 512 blocks x 256 thr. Block covers 64 cells;
// thread (cell = bid*64 + (t&63), part = t>>6) sums 36 chunks; LDS combine
// of the 4 parts; squash over e (16-lane groups, cells 16-aligned).
// mode 0: vacc = v ; 1: vacc += v ; 2: out = v
__global__ __launch_bounds__(256)
void reduce_squash(const float* __restrict__ partial, float* __restrict__ vacc,
                   float* __restrict__ out, int mode)
{
  __shared__ float sm[256];
  const int t    = threadIdx.x;
  const int cell = blockIdx.x*64 + (t & 63);
  const int part = t >> 6;
  const float* p = partial + (size_t)(part*36) * SCE + cell;
  float s = 0.f;
#pragma unroll 6
  for (int k = 0; k < 36; ++k) s += p[(size_t)k * SCE];
  sm[t] = s;
  __syncthreads();
  if (t < 64) {
    float tot = sm[t] + sm[t+64] + sm[t+128] + sm[t+192];
    float sq = tot * tot;
    sq += __shfl_xor(sq, 1); sq += __shfl_xor(sq, 2);
    sq += __shfl_xor(sq, 4); sq += __shfl_xor(sq, 8);
    float scale = sq / (1.f + sq) / (sqrtf(sq) + 1e-8f);
    float v = scale * tot;
    if (mode == 0)      vacc[cell] = v;
    else if (mode == 1) vacc[cell] += v;
    else                out[cell]  = v;
  }
}

extern "C" void kernel_launch(void* const* d_in, const int* in_sizes, int n_in,
                              void* d_out, int out_size, void* d_ws, size_t ws_size,
                              hipStream_t stream)
{
  const float* x = (const float*)d_in[0];
  const float* W = (const float*)d_in[1];
  float* out     = (float*)d_out;

  float* partial = (float*)d_ws;                   // NIC*SCE f32 = 18.9 MB
  float* vacc    = partial + (size_t)NIC * SCE;    // SCE f32 = 128 KB

  dim3 pg(NIC * (B_/BC_));                         // 1152 blocks
  const int rg = SCE / 64;                         // 512 blocks

  // iter 0: uniform coefficients (softmax of zeros = 1/32)
  caps_pass<false><<<pg, 256, 0, stream>>>(x, W, nullptr, partial);
  reduce_squash<<<rg, 256, 0, stream>>>(partial, vacc, nullptr, 0);
  // iter 1: logits = u_hat . v0
  caps_pass<true ><<<pg, 256, 0, stream>>>(x, W, vacc, partial);
  reduce_squash<<<rg, 256, 0, stream>>>(partial, vacc, nullptr, 1);
  // iter 2: logits = u_hat . (v0+v1)
  caps_pass<true ><<<pg, 256, 0, stream>>>(x, W, vacc, partial);
  reduce_squash<<<rg, 256, 0, stream>>>(partial, vacc, out, 2);
}

// Round 9
// 73.994 us; speedup vs baseline: 5.5273x; 1.2017x over previous
//
#include <hip/hip_runtime.h>
#include <hip/hip_fp16.h>

#define B_ 64
#define I_ 1152
#define C_ 32
#define E_ 16
#define D_ 8
#define BC_ 8                // batch rows per block (4 waves, j=2 each)
#define ICt 12               // i's per block
#define NIC (I_/ICt)         // 96 i-chunks
#define ICX (NIC/8)          // 12 i-chunks per XCD slab
#define WROW4 (C_*D_*E_/4)   // 1024 float4 per W[i]
#define SCE (B_*C_*E_)       // 32768 s-elements
#define SCE2 (SCE/2)         // 16384 half2 pairs

// async global->LDS DMA, 16B per lane (dest = wave-uniform base + lane*16)
__device__ __forceinline__ void gload_lds16(const void* g, void* l) {
  typedef __attribute__((address_space(1))) const void GV;
  typedef __attribute__((address_space(3))) void LV;
  __builtin_amdgcn_global_load_lds((GV*)g, (LV*)l, 16, 0, 0);
}

#define WAITVM(N) do { asm volatile("s_waitcnt vmcnt(" #N ")" ::: "memory"); \
                       __builtin_amdgcn_sched_barrier(0); } while (0)
#define WAITLG0()  do { asm volatile("s_waitcnt lgkmcnt(0)" ::: "memory");   \
                       __builtin_amdgcn_sched_barrier(0); } while (0)

// Recompute u_hat[b,i,c,e] = sum_d x[b,i,d]*W[i,c,d,e]; coupling coef (uniform
// or softmax_c of u_hat . vacc, no max-subtraction: logits bounded, f32 exp
// safe); accumulate partial s (f16-packed) over the block's i-chunk.
// 256 thr: c=t&31, eh=(t>>5)&1, bq=t>>6, j=0..1 -> b = b0 + bq*2 + j.
// W staged via global_load_lds into a 3-buffer, 2-deep pipeline with counted
// vmcnt + raw barriers (T3/T4): per-period wait targets W(p) issued TWO
// periods earlier, so W(p+1),W(p+2) stay in flight across barriers.
// Grid = 96 ic x 8 b-slabs = 768 blocks = EXACTLY 3 resident blocks/CU
// (LDS 51KB) -> no scheduling tail.
// Swizzle (quad rotated by c-row) on the GLOBAL source address (rule 21).
// Block map (XCD slab, perf-only): xcd=bid&7 -> ic slab; slab W (2.36MB)
// stays L2-resident across its 8 b-slabs.
template<bool ROUTE>
__global__ __launch_bounds__(256)
void caps_pass(const float* __restrict__ x, const float* __restrict__ W,
               const float* __restrict__ vacc, __half* __restrict__ partial)
{
  __shared__ float4 Wl[3][C_*32];     // 3 x 16KB W buffers
  __shared__ float4 xl[BC_*ICt*2];    // 192 float4 (3KB)

  const int t   = threadIdx.x;
  const int c   = t & 31;
  const int eh  = (t >> 5) & 1;
  const int bq  = t >> 6;
  const int xcd = blockIdx.x & 7;
  const int sl  = blockIdx.x >> 3;    // 0..95
  const int ic  = xcd * ICX + (sl >> 3);
  const int b0  = (sl & 7) * BC_;
  const int i0  = ic * ICt;

  // DMA staging map: LDS linear float4 index g = t + 256k; row cc = g>>5,
  // slot = g&31 = c. Want Wl[cc*32 + ((q+cc)&31)] = wg[cc*32+q]
  // => src quad f = cc*32 + ((c - cc)&31).
  int fsrc[4];
#pragma unroll
  for (int k = 0; k < 4; ++k) {
    int cc = (t >> 5) + 8*k;
    fsrc[k] = cc*32 + ((c - cc) & 31);
  }

  float vr[2][8];
  if (ROUTE) {
#pragma unroll
    for (int j = 0; j < 2; ++j) {
      const float4* vp = (const float4*)(vacc + (((size_t)(b0 + bq*2 + j)*C_ + c)*E_ + eh*8));
      float4 a = vp[0], b = vp[1];
      vr[j][0]=a.x; vr[j][1]=a.y; vr[j][2]=a.z; vr[j][3]=a.w;
      vr[j][4]=b.x; vr[j][5]=b.y; vr[j][6]=b.z; vr[j][7]=b.w;
    }
  }

  // stage x for all ICt i's (192 float4: 8 b x 24)
  if (t < BC_*ICt*2) {
    int b = t / (ICt*2), r = t % (ICt*2);
    xl[t] = ((const float4*)x)[ ((size_t)(b0 + b)*I_ + i0)*2 + r ];
  }

  const float4* wg = (const float4*)(W + (size_t)i0 * (C_*D_*E_));
  // prologue: issue W[i0]->buf0 and W[i0+1]->buf1 (stay in flight)
#pragma unroll
  for (int k = 0; k < 4; ++k) gload_lds16(wg + fsrc[k],          &Wl[0][t + 256*k]);
#pragma unroll
  for (int k = 0; k < 4; ++k) gload_lds16(wg + WROW4 + fsrc[k],  &Wl[1][t + 256*k]);

  float acc[2][8];
#pragma unroll
  for (int j = 0; j < 2; ++j)
#pragma unroll
    for (int e = 0; e < 8; ++e) acc[j][e] = 0.f;

  int cur = 0;
  for (int ii = 0; ii < ICt; ++ii) {
    // barrier 1: all waves done READING the buffer DMA(ii+2) will overwrite
    // (and, at ii=0, xl ds_writes drained)
    WAITLG0();
    __builtin_amdgcn_s_barrier();
    __builtin_amdgcn_sched_barrier(0);

    if (ii + 2 < ICt) {                          // issue 2-ahead prefetch
      int pre = cur + 2; if (pre >= 3) pre -= 3;
      const float4* wn = wg + (size_t)(ii + 2) * WROW4;
#pragma unroll
      for (int k = 0; k < 4; ++k)
        gload_lds16(wn + fsrc[k], &Wl[pre][t + 256*k]);
    }

    // wait for OWN W(ii) batch (leaves W(ii+1),W(ii+2) in flight), then
    // barrier 2: every wave's W(ii) quarter has landed.
    if (ii < ICt - 2)       WAITVM(8);
    else if (ii == ICt - 2) WAITVM(4);
    else                    WAITVM(0);
    __builtin_amdgcn_s_barrier();
    __builtin_amdgcn_sched_barrier(0);

    float xv[2][8];
#pragma unroll
    for (int j = 0; j < 2; ++j) {
      float4 a = xl[(bq*2 + j)*(ICt*2) + ii*2 + 0];
      float4 b = xl[(bq*2 + j)*(ICt*2) + ii*2 + 1];
      xv[j][0]=a.x; xv[j][1]=a.y; xv[j][2]=a.z; xv[j][3]=a.w;
      xv[j][4]=b.x; xv[j][5]=b.y; xv[j][6]=b.z; xv[j][7]=b.w;
    }

    float uh[2][8];
#pragma unroll
    for (int j = 0; j < 2; ++j)
#pragma unroll
      for (int e = 0; e < 8; ++e) uh[j][e] = 0.f;

#pragma unroll
    for (int d = 0; d < D_; ++d) {
#pragma unroll
      for (int qq = 0; qq < 2; ++qq) {
        float4 wv = Wl[cur][c*32 + (((d*4 + eh*2 + qq) + c) & 31)];
        const int eb = qq*4;
#pragma unroll
        for (int j = 0; j < 2; ++j) {
          uh[j][eb+0] = fmaf(xv[j][d], wv.x, uh[j][eb+0]);
          uh[j][eb+1] = fmaf(xv[j][d], wv.y, uh[j][eb+1]);
          uh[j][eb+2] = fmaf(xv[j][d], wv.z, uh[j][eb+2]);
          uh[j][eb+3] = fmaf(xv[j][d], wv.w, uh[j][eb+3]);
        }
      }
    }

    float coef[2];
    if (ROUTE) {
#pragma unroll
      for (int j = 0; j < 2; ++j) {
        float lg = 0.f;
#pragma unroll
        for (int e = 0; e < 8; ++e) lg = fmaf(uh[j][e], vr[j][e], lg);
        lg += __shfl_xor(lg, 32, 64);            // combine e-halves
        float p = __expf(lg);                    // no max-sub: |lg| bounded
        float s = p;
#pragma unroll
        for (int mk = 16; mk >= 1; mk >>= 1) s += __shfl_xor(s, mk, 64);
        coef[j] = p * __builtin_amdgcn_rcpf(s);
      }
    } else {
#pragma unroll
      for (int j = 0; j < 2; ++j) coef[j] = (1.0f / C_);
    }

#pragma unroll
    for (int j = 0; j < 2; ++j)
#pragma unroll
      for (int e = 0; e < 8; ++e) acc[j][e] = fmaf(coef[j], uh[j][e], acc[j][e]);

    cur = (cur + 1 == 3) ? 0 : cur + 1;
  }

  // partial s (f16) for this i-chunk: [NIC][B][C][E] halfs, 16B/j store
#pragma unroll
  for (int j = 0; j < 2; ++j) {
    size_t base = ((size_t)ic * B_ + (b0 + bq*2 + j)) * (C_*E_) + (size_t)c*E_ + eh*8;
    __half2 h0 = __float22half2_rn({acc[j][0], acc[j][1]});
    __half2 h1 = __float22half2_rn({acc[j][2], acc[j][3]});
    __half2 h2 = __float22half2_rn({acc[j][4], acc[j][5]});
    __half2 h3 = __float22half2_rn({acc[j][6], acc[j][7]});
    __half2* dst = (__half2*)(partial + base);
    dst[0] = h0; dst[1] = h1; dst[2] = h2; dst[3] = h3;   // contiguous 16B
  }
}

// Fused reduce+squash on f16 partial: grid 256 blocks x 256 thr. Block covers
// 64 half2 pairs (128 cells); thread (pair = bid*64 + (t&63), part = t>>6)
// sums 24 chunks as float2; LDS combine of 4 parts; squash over e (16 cells =
// 8 pairs = 8-lane shfl group). mode 0: vacc = v ; 1: vacc += v ; 2: out = v
__global__ __launch_bounds__(256)
void reduce_squash(const __half2* __restrict__ partial, float* __restrict__ vacc,
                   float* __restrict__ out, int mode)
{
  __shared__ float2 sm[256];
  const int t    = threadIdx.x;
  const int pair = blockIdx.x*64 + (t & 63);
  const int part = t >> 6;
  const __half2* p = partial + (size_t)(part*(NIC/4)) * SCE2 + pair;
  float2 s = {0.f, 0.f};
#pragma unroll 6
  for (int k = 0; k < NIC/4; ++k) {
    float2 f = __half22float2(p[(size_t)k * SCE2]);
    s.x += f.x; s.y += f.y;
  }
  sm[t] = s;
  __syncthreads();
  if (t < 64) {
    float2 a = sm[t], b = sm[t+64], c2 = sm[t+128], d = sm[t+192];
    float2 tot = {a.x+b.x+c2.x+d.x, a.y+b.y+c2.y+d.y};
    float sq = tot.x*tot.x + tot.y*tot.y;
    sq += __shfl_xor(sq, 1); sq += __shfl_xor(sq, 2); sq += __shfl_xor(sq, 4);
    float scale = sq / (1.f + sq) / (sqrtf(sq) + 1e-8f);
    float vx = scale * tot.x, vy = scale * tot.y;
    const int cell = pair * 2;
    if (mode == 0)      { vacc[cell] = vx;  vacc[cell+1] = vy;  }
    else if (mode == 1) { vacc[cell] += vx; vacc[cell+1] += vy; }
    else                { out[cell]  = vx;  out[cell+1]  = vy;  }
  }
}

extern "C" void kernel_launch(void* const* d_in, const int* in_sizes, int n_in,
                              void* d_out, int out_size, void* d_ws, size_t ws_size,
                              hipStream_t stream)
{
  const float* x = (const float*)d_in[0];
  const float* W = (const float*)d_in[1];
  float* out     = (float*)d_out;

  __half* partial = (__half*)d_ws;                          // NIC*SCE halfs = 6.3 MB
  float*  vacc    = (float*)((char*)d_ws + (size_t)NIC*SCE*sizeof(__half));

  dim3 pg(NIC * (B_/BC_));                                  // 768 blocks (3/CU exact)
  const int rg = SCE2 / 64;                                 // 256 blocks

  // iter 0: uniform coefficients (softmax of zeros = 1/32)
  caps_pass<false><<<pg, 256, 0, stream>>>(x, W, nullptr, partial);
  reduce_squash<<<rg, 256, 0, stream>>>((const __half2*)partial, vacc, nullptr, 0);
  // iter 1: logits = u_hat . v0
  caps_pass<true ><<<pg, 256, 0, stream>>>(x, W, vacc, partial);
  reduce_squash<<<rg, 256, 0, stream>>>((const __half2*)partial, vacc, nullptr, 1);
  // iter 2: logits = u_hat . (v0+v1)
  caps_pass<true ><<<pg, 256, 0, stream>>>(x, W, vacc, partial);
  reduce_squash<<<rg, 256, 0, stream>>>((const __half2*)partial, vacc, out, 2);
}